// Round 4
// baseline (736.294 us; speedup 1.0000x reference)
//
#include <hip/hip_runtime.h>
#include <math.h>

#define TSEQ   2048
#define NBATCH 4
#define NHEAD  16
#define HDIM   64
#define DMODEL 1024
#define MROWS  (NBATCH * TSEQ)   // 8192
// fold 8 * log2(e) into Q so softmax runs in exp2 domain (v_exp_f32 native)
#define QSCALE 11.541560327111707f

typedef float f32x4  __attribute__((ext_vector_type(4)));
typedef short bf16x8 __attribute__((ext_vector_type(8)));
typedef _Float16 f16x8 __attribute__((ext_vector_type(8)));

static __device__ __forceinline__ short f2bf(float f) {  // RNE float->bf16
    union { float f; unsigned u; } a; a.f = f;
    unsigned r = a.u + 0x7FFFu + ((a.u >> 16) & 1u);
    return (short)(r >> 16);
}
static __device__ __forceinline__ float bf2f(short s) {
    union { unsigned u; float f; } a; a.u = ((unsigned)(unsigned short)s) << 16;
    return a.f;
}

// async global->LDS, 16B per lane; LDS dest = wave-uniform base + lane*16
static __device__ __forceinline__ void async_copy16(short* lds, const short* g) {
    __builtin_amdgcn_global_load_lds(
        (const __attribute__((address_space(1))) void*)g,
        (__attribute__((address_space(3))) void*)lds, 16, 0, 0);
}

// ---------------------------------------------------------------------------
// One fused fp32 -> (hi,lo) bf16 splitter for X, Wq, Wk, Wv.
// gid is in float4 units: [0, 2M) -> X; then 256K each for Wq/Wk/Wv.
// ---------------------------------------------------------------------------
#define X_F4 (MROWS * DMODEL / 4)          // 2097152
#define W_F4 (DMODEL * DMODEL / 4)         // 262144  (1<<18)
__global__ __launch_bounds__(256) void split_all(
    const float* __restrict__ x,
    const float* __restrict__ wq, const float* __restrict__ wk,
    const float* __restrict__ wv,
    short* __restrict__ Xhi, short* __restrict__ Xlo,
    short* __restrict__ Whi, short* __restrict__ Wlo)
{
    int gid = blockIdx.x * 256 + threadIdx.x;
    const float* src; short* dh; short* dl; int off;
    if (gid < X_F4) {
        src = x; dh = Xhi; dl = Xlo; off = gid;
    } else {
        int r = gid - X_F4;
        int z = r >> 18;                   // 0..2
        off = r & (W_F4 - 1);
        src = (z == 0) ? wq : (z == 1) ? wk : wv;
        dh = Whi + (size_t)z * DMODEL * DMODEL;
        dl = Wlo + (size_t)z * DMODEL * DMODEL;
    }
    float4 v = ((const float4*)src)[off];
    float f[4] = {v.x, v.y, v.z, v.w};
    short h[4], l[4];
    #pragma unroll
    for (int c = 0; c < 4; c++) {
        h[c] = f2bf(f[c]);
        l[c] = f2bf(f[c] - bf2f(h[c]));
    }
    *(float2*)(dh + (size_t)off * 4) = *(const float2*)h;
    *(float2*)(dl + (size_t)off * 4) = *(const float2*)l;
}

// ---------------------------------------------------------------------------
// Split-bf16 MFMA GEMM (unchanged structure from R3): Y = X W^T + b.
// z=0 -> Qhi/Qlo bf16 [bh][T][64] (scaled by QSCALE)
// z=1 -> Khi/Klo bf16 [bh][T][64]
// z=2 -> V^T   fp16  [bh][64][T]   (transposed for attn B-frag reads;
//        scattered 2B stores merge in write-back L2 within the 16KB tile set)
// ---------------------------------------------------------------------------
__global__ __launch_bounds__(256, 2) void qkv_gemm_mfma(
    const short* __restrict__ Xhi, const short* __restrict__ Xlo,
    const short* __restrict__ Wh3, const short* __restrict__ Wl3,  // [3][N][K]
    const float* __restrict__ bq, const float* __restrict__ bk,
    const float* __restrict__ bv,
    short* __restrict__ Qhi, short* __restrict__ Qlo,
    short* __restrict__ Khi, short* __restrict__ Klo,
    _Float16* __restrict__ VgT)
{
    const int z = blockIdx.z;
    const short* Wh = Wh3 + (size_t)z * DMODEL * DMODEL;
    const short* Wl = Wl3 + (size_t)z * DMODEL * DMODEL;
    const float* bias = (z == 0) ? bq : (z == 1) ? bk : bv;

    __shared__ __align__(16) short Ah[128 * 32];
    __shared__ __align__(16) short Al[128 * 32];
    __shared__ __align__(16) short Bh[128 * 32];
    __shared__ __align__(16) short Bl[128 * 32];

    const int tid  = threadIdx.x;
    const int w    = tid >> 6;
    const int lane = tid & 63;
    const int t    = lane & 15;
    const int quad = lane >> 4;
    const int wm   = w >> 1, wn = w & 1;
    const int bm   = blockIdx.y * 128;
    const int bn   = blockIdx.x * 128;

    const int r_local = lane >> 2;
    const int kq      = (lane & 3) ^ ((r_local >> 1) & 3);
    const int row0    = w * 32 + r_local;
    const int slotq   = (quad ^ ((t >> 1) & 3)) * 8;

    f32x4 acc[4][4];
    #pragma unroll
    for (int i = 0; i < 4; i++)
        #pragma unroll
        for (int j = 0; j < 4; j++) acc[i][j] = (f32x4){0.f, 0.f, 0.f, 0.f};

    for (int k0 = 0; k0 < DMODEL; k0 += 32) {
        __syncthreads();
        #pragma unroll
        for (int i = 0; i < 2; i++) {
            int row = row0 + i * 16;
            size_t ga = (size_t)(bm + row) * DMODEL + k0 + kq * 8;
            size_t gb = (size_t)(bn + row) * DMODEL + k0 + kq * 8;
            int ldst = (w * 32 + i * 16) * 32;
            async_copy16(&Ah[ldst], Xhi + ga);
            async_copy16(&Al[ldst], Xlo + ga);
            async_copy16(&Bh[ldst], Wh + gb);
            async_copy16(&Bl[ldst], Wl + gb);
        }
        __syncthreads();

        bf16x8 ah[4], al[4], bh[4], bl[4];
        #pragma unroll
        for (int mt = 0; mt < 4; mt++) {
            int off = (wm * 64 + mt * 16 + t) * 32 + slotq;
            ah[mt] = *(const bf16x8*)&Ah[off];
            al[mt] = *(const bf16x8*)&Al[off];
        }
        #pragma unroll
        for (int nt = 0; nt < 4; nt++) {
            int off = (wn * 64 + nt * 16 + t) * 32 + slotq;
            bh[nt] = *(const bf16x8*)&Bh[off];
            bl[nt] = *(const bf16x8*)&Bl[off];
        }
        #pragma unroll
        for (int mt = 0; mt < 4; mt++)
            #pragma unroll
            for (int nt = 0; nt < 4; nt++) {
                acc[mt][nt] = __builtin_amdgcn_mfma_f32_16x16x32_bf16(
                    al[mt], bh[nt], acc[mt][nt], 0, 0, 0);
                acc[mt][nt] = __builtin_amdgcn_mfma_f32_16x16x32_bf16(
                    ah[mt], bl[nt], acc[mt][nt], 0, 0, 0);
                acc[mt][nt] = __builtin_amdgcn_mfma_f32_16x16x32_bf16(
                    ah[mt], bh[nt], acc[mt][nt], 0, 0, 0);
            }
    }

    const float scale = (z == 0) ? QSCALE : 1.0f;
    const int n_base = bn + wn * 64;
    const int h_head = n_base >> 6;     // 64-aligned strip -> single head
    float bvs[4];
    #pragma unroll
    for (int nt = 0; nt < 4; nt++)
        bvs[nt] = bias[n_base + nt * 16 + t];

    #pragma unroll
    for (int mt = 0; mt < 4; mt++) {
        #pragma unroll
        for (int r = 0; r < 4; r++) {
            int m  = bm + wm * 64 + mt * 16 + quad * 4 + r;
            int b_ = m >> 11;
            int t_ = m & 2047;
            #pragma unroll
            for (int nt = 0; nt < 4; nt++) {
                int d = nt * 16 + t;
                float v = (acc[mt][nt][r] + bvs[nt]) * scale;
                if (z == 2) {
                    size_t idx = ((size_t)(b_ * NHEAD + h_head) * HDIM + d) * TSEQ + t_;
                    VgT[idx] = (_Float16)v;
                } else {
                    size_t idx = (((size_t)(b_ * NHEAD + h_head) * TSEQ + t_) << 6) + d;
                    short hb = f2bf(v);
                    short lb = f2bf(v - bf2f(hb));
                    if (z == 0) { Qhi[idx] = hb; Qlo[idx] = lb; }
                    else        { Khi[idx] = hb; Klo[idx] = lb; }
                }
            }
        }
    }
}

// ---------------------------------------------------------------------------
// MFMA flash attention v2.
//  - Q-tile 128 rows/block (4 waves x 2 m-tiles), K-tile 64.
//  - Register-prefetch of next K tile (m97-style pipeline).
//  - V^T read directly from global (L2-hot), no V in LDS.
//  - QK^T: split-bf16 (3 MFMA); P,V: fp16; row-sum via ones-MFMA column.
// LDS: Kh/Kl 64x72 bf16 + P 128x72 fp16 = 36 KB.
// ---------------------------------------------------------------------------
__global__ __launch_bounds__(256, 3) void attn_fwd(
    const short* __restrict__ Qhi, const short* __restrict__ Qlo,
    const short* __restrict__ Khi, const short* __restrict__ Klo,
    const _Float16* __restrict__ VgT,   // [bh][64][T]
    float* __restrict__ out)            // [B][T][1024]
{
    __shared__ __align__(16) short    Kh_lds[64 * 72];
    __shared__ __align__(16) short    Kl_lds[64 * 72];
    __shared__ __align__(16) _Float16 P_lds [128 * 72];

    const int tid  = threadIdx.x;
    const int qb   = 15 - blockIdx.x;      // heavy blocks first
    const int bh   = blockIdx.y;
    const int b    = bh >> 4, h = bh & 15;
    const int w    = tid >> 6;
    const int lane = tid & 63;
    const int t    = lane & 15;
    const int quad = lane >> 4;

    // Q A-frags: rows qb*128 + w*32 + mt*16 + t
    bf16x8 qh[2][2], ql[2][2];
    #pragma unroll
    for (int mt = 0; mt < 2; mt++) {
        size_t qrow = (size_t)bh * TSEQ + qb * 128 + w * 32 + mt * 16 + t;
        #pragma unroll
        for (int dh = 0; dh < 2; dh++) {
            qh[mt][dh] = *(const bf16x8*)(Qhi + qrow * 64 + dh * 32 + quad * 8);
            ql[mt][dh] = *(const bf16x8*)(Qlo + qrow * 64 + dh * 32 + quad * 8);
        }
    }

    f16x8 ones;
    #pragma unroll
    for (int i = 0; i < 8; i++) ones[i] = (_Float16)1.0f;

    f32x4 O[2][4], Ol[2];
    #pragma unroll
    for (int mt = 0; mt < 2; mt++) {
        Ol[mt] = (f32x4){0.f, 0.f, 0.f, 0.f};
        #pragma unroll
        for (int j = 0; j < 4; j++) O[mt][j] = (f32x4){0.f, 0.f, 0.f, 0.f};
    }
    float m_st[2][4];
    #pragma unroll
    for (int mt = 0; mt < 2; mt++)
        #pragma unroll
        for (int r = 0; r < 4; r++) m_st[mt][r] = -1e30f;

    const int ktmax = 2 * qb + 1;

    // K staging geometry: chunk c = tid + i*256; row=c>>3, c8=c&7
    const int s_row = tid >> 3, s_c8 = tid & 7;

    // prologue prefetch (tile 0)
    float4 pk[4];
    {
        size_t g0 = ((size_t)bh * TSEQ + s_row) * 64 + s_c8 * 8;
        pk[0] = *(const float4*)(Khi + g0);
        pk[2] = *(const float4*)(Klo + g0);
        size_t g1 = ((size_t)bh * TSEQ + 32 + s_row) * 64 + s_c8 * 8;
        pk[1] = *(const float4*)(Khi + g1);
        pk[3] = *(const float4*)(Klo + g1);
    }

    for (int kt = 0; kt <= ktmax; kt++) {
        __syncthreads();   // previous tile's LDS reads complete
        *(float4*)&Kh_lds[s_row * 72 + s_c8 * 8]        = pk[0];
        *(float4*)&Kh_lds[(32 + s_row) * 72 + s_c8 * 8] = pk[1];
        *(float4*)&Kl_lds[s_row * 72 + s_c8 * 8]        = pk[2];
        *(float4*)&Kl_lds[(32 + s_row) * 72 + s_c8 * 8] = pk[3];
        __syncthreads();

        if (kt < ktmax) {   // prefetch next tile into regs (waited next iter)
            size_t g0 = ((size_t)bh * TSEQ + (kt + 1) * 64 + s_row) * 64 + s_c8 * 8;
            pk[0] = *(const float4*)(Khi + g0);
            pk[2] = *(const float4*)(Klo + g0);
            size_t g1 = ((size_t)bh * TSEQ + (kt + 1) * 64 + 32 + s_row) * 64 + s_c8 * 8;
            pk[1] = *(const float4*)(Khi + g1);
            pk[3] = *(const float4*)(Klo + g1);
        }

        // V B-frags direct from global (L2-hot), issued early to hide latency
        f16x8 vf[4][2];
        #pragma unroll
        for (int ct2 = 0; ct2 < 4; ct2++) {
            const _Float16* vb = VgT + ((size_t)bh * HDIM + ct2 * 16 + t) * TSEQ + kt * 64;
            vf[ct2][0] = *(const f16x8*)(vb + quad * 8);
            vf[ct2][1] = *(const f16x8*)(vb + 32 + quad * 8);
        }

        // ---- per m-tile: QK^T, mask, online softmax, P write ----
        #pragma unroll
        for (int mt = 0; mt < 2; mt++) {
            f32x4 S[4];
            #pragma unroll
            for (int ct = 0; ct < 4; ct++) {
                S[ct] = (f32x4){0.f, 0.f, 0.f, 0.f};
                #pragma unroll
                for (int dh = 0; dh < 2; dh++) {
                    bf16x8 kh = *(const bf16x8*)&Kh_lds[(ct*16 + t)*72 + dh*32 + quad*8];
                    bf16x8 kl = *(const bf16x8*)&Kl_lds[(ct*16 + t)*72 + dh*32 + quad*8];
                    S[ct] = __builtin_amdgcn_mfma_f32_16x16x32_bf16(ql[mt][dh], kh, S[ct], 0, 0, 0);
                    S[ct] = __builtin_amdgcn_mfma_f32_16x16x32_bf16(qh[mt][dh], kl, S[ct], 0, 0, 0);
                    S[ct] = __builtin_amdgcn_mfma_f32_16x16x32_bf16(qh[mt][dh], kh, S[ct], 0, 0, 0);
                }
            }

            if (kt >= 2 * qb) {   // diagonal super-columns: causal mask
                int cbase = (kt - 2 * qb) * 64;
                #pragma unroll
                for (int ct = 0; ct < 4; ct++) {
                    int col = cbase + ct * 16 + t;
                    #pragma unroll
                    for (int r = 0; r < 4; r++)
                        if (col > w * 32 + mt * 16 + quad * 4 + r) S[ct][r] = -1e30f;
                }
            }

            #pragma unroll
            for (int r = 0; r < 4; r++) {
                float mx = fmaxf(fmaxf(S[0][r], S[1][r]), fmaxf(S[2][r], S[3][r]));
                mx = fmaxf(mx, __shfl_xor(mx, 1, 64));
                mx = fmaxf(mx, __shfl_xor(mx, 2, 64));
                mx = fmaxf(mx, __shfl_xor(mx, 4, 64));
                mx = fmaxf(mx, __shfl_xor(mx, 8, 64));
                float mn = fmaxf(m_st[mt][r], mx);
                float al = exp2f(m_st[mt][r] - mn);
                m_st[mt][r] = mn;
                #pragma unroll
                for (int ct = 0; ct < 4; ct++)
                    S[ct][r] = exp2f(S[ct][r] - mn);
                Ol[mt][r] *= al;
                #pragma unroll
                for (int ct2 = 0; ct2 < 4; ct2++) O[mt][ct2][r] *= al;
            }

            // P: C-layout -> A-layout via wave-private LDS strip (fp16)
            #pragma unroll
            for (int ct = 0; ct < 4; ct++)
                #pragma unroll
                for (int r = 0; r < 4; r++)
                    P_lds[(w*32 + mt*16 + quad*4 + r) * 72 + ct*16 + t] =
                        (_Float16)S[ct][r];
        }

        // ---- PV + row-sum (fp16 MFMA) ----
        f16x8 pf[2][2];
        #pragma unroll
        for (int mt = 0; mt < 2; mt++)
            #pragma unroll
            for (int dh = 0; dh < 2; dh++)
                pf[mt][dh] = *(const f16x8*)&P_lds[(w*32 + mt*16 + t)*72 + dh*32 + quad*8];

        #pragma unroll
        for (int mt = 0; mt < 2; mt++) {
            #pragma unroll
            for (int ct2 = 0; ct2 < 4; ct2++) {
                O[mt][ct2] = __builtin_amdgcn_mfma_f32_16x16x32_f16(pf[mt][0], vf[ct2][0], O[mt][ct2], 0, 0, 0);
                O[mt][ct2] = __builtin_amdgcn_mfma_f32_16x16x32_f16(pf[mt][1], vf[ct2][1], O[mt][ct2], 0, 0, 0);
            }
            Ol[mt] = __builtin_amdgcn_mfma_f32_16x16x32_f16(pf[mt][0], ones, Ol[mt], 0, 0, 0);
            Ol[mt] = __builtin_amdgcn_mfma_f32_16x16x32_f16(pf[mt][1], ones, Ol[mt], 0, 0, 0);
        }
    }

    // epilogue: normalize, write [B][T][H*64] fp32
    #pragma unroll
    for (int mt = 0; mt < 2; mt++) {
        float* ob = out + ((size_t)b * TSEQ + qb * 128 + w * 32 + mt * 16 + quad * 4) * DMODEL
                  + h * 64;
        #pragma unroll
        for (int r = 0; r < 4; r++) {
            float inv = 1.0f / Ol[mt][r];
            #pragma unroll
            for (int ct2 = 0; ct2 < 4; ct2++)
                ob[(size_t)r * DMODEL + ct2 * 16 + t] = O[mt][ct2][r] * inv;
        }
    }
}

// ---------------------------------------------------------------------------
extern "C" void kernel_launch(void* const* d_in, const int* in_sizes, int n_in,
                              void* d_out, int out_size, void* d_ws, size_t ws_size,
                              hipStream_t stream)
{
    const float* x  = (const float*)d_in[0];
    const float* Wq = (const float*)d_in[1];
    const float* bq = (const float*)d_in[2];
    const float* Wk = (const float*)d_in[3];
    const float* bk = (const float*)d_in[4];
    const float* Wv = (const float*)d_in[5];
    const float* bv = (const float*)d_in[6];

    const size_t TEN = (size_t)MROWS * DMODEL;   // 8M
    const size_t WEN = (size_t)DMODEL * DMODEL;  // 1M
    short* Xhi = (short*)d_ws;
    short* Xlo = Xhi + TEN;
    short* Whi = Xlo + TEN;
    short* Wlo = Whi + 3 * WEN;
    short* Qhi = Wlo + 3 * WEN;
    short* Qlo = Qhi + TEN;
    short* Khi = Qlo + TEN;
    short* Klo = Khi + TEN;
    _Float16* VgT = (_Float16*)(Klo + TEN);
    float* out = (float*)d_out;

    int nsplit = (X_F4 + 3 * W_F4) / 256;
    split_all<<<nsplit, 256, 0, stream>>>(x, Wq, Wk, Wv, Xhi, Xlo, Whi, Wlo);

    dim3 gg(DMODEL / 128, MROWS / 128, 3);
    qkv_gemm_mfma<<<gg, 256, 0, stream>>>(Xhi, Xlo, Whi, Wlo, bq, bk, bv,
                                          Qhi, Qlo, Khi, Klo, VgT);

    dim3 ga(TSEQ / 128, NBATCH * NHEAD);
    attn_fwd<<<ga, 256, 0, stream>>>(Qhi, Qlo, Khi, Klo, VgT, out);
}

// Round 6
// 513.514 us; speedup vs baseline: 1.4338x; 1.4338x over previous
//
#include <hip/hip_runtime.h>
#include <math.h>

#define TSEQ   2048
#define NBATCH 4
#define NHEAD  16
#define HDIM   64
#define DMODEL 1024
#define MROWS  (NBATCH * TSEQ)   // 8192
// fold 8 * log2(e) into Q so softmax runs in exp2 domain (v_exp_f32 native)
#define QSCALE 11.541560327111707f

typedef float f32x4  __attribute__((ext_vector_type(4)));
typedef short bf16x8 __attribute__((ext_vector_type(8)));
typedef _Float16 f16x8 __attribute__((ext_vector_type(8)));

static __device__ __forceinline__ short f2bf(float f) {  // RNE float->bf16
    union { float f; unsigned u; } a; a.f = f;
    unsigned r = a.u + 0x7FFFu + ((a.u >> 16) & 1u);
    return (short)(r >> 16);
}
static __device__ __forceinline__ float bf2f(short s) {
    union { unsigned u; float f; } a; a.u = ((unsigned)(unsigned short)s) << 16;
    return a.f;
}

// async global->LDS, 16B per lane; LDS dest = wave-uniform base + lane*16
static __device__ __forceinline__ void async_copy16(void* lds, const void* g) {
    __builtin_amdgcn_global_load_lds(
        (const __attribute__((address_space(1))) void*)g,
        (__attribute__((address_space(3))) void*)lds, 16, 0, 0);
}

// ---------------------------------------------------------------------------
// One fused fp32 -> (hi,lo) bf16 splitter for X, Wq, Wk, Wv.
// ---------------------------------------------------------------------------
#define X_F4 (MROWS * DMODEL / 4)          // 2097152
#define W_F4 (DMODEL * DMODEL / 4)         // 262144  (1<<18)
__global__ __launch_bounds__(256) void split_all(
    const float* __restrict__ x,
    const float* __restrict__ wq, const float* __restrict__ wk,
    const float* __restrict__ wv,
    short* __restrict__ Xhi, short* __restrict__ Xlo,
    short* __restrict__ Whi, short* __restrict__ Wlo)
{
    int gid = blockIdx.x * 256 + threadIdx.x;
    const float* src; short* dh; short* dl; int off;
    if (gid < X_F4) {
        src = x; dh = Xhi; dl = Xlo; off = gid;
    } else {
        int r = gid - X_F4;
        int z = r >> 18;                   // 0..2
        off = r & (W_F4 - 1);
        src = (z == 0) ? wq : (z == 1) ? wk : wv;
        dh = Whi + (size_t)z * DMODEL * DMODEL;
        dl = Wlo + (size_t)z * DMODEL * DMODEL;
    }
    float4 v = ((const float4*)src)[off];
    float f[4] = {v.x, v.y, v.z, v.w};
    short h[4], l[4];
    #pragma unroll
    for (int c = 0; c < 4; c++) {
        h[c] = f2bf(f[c]);
        l[c] = f2bf(f[c] - bf2f(h[c]));
    }
    *(float2*)(dh + (size_t)off * 4) = *(const float2*)h;
    *(float2*)(dl + (size_t)off * 4) = *(const float2*)l;
}

// ---------------------------------------------------------------------------
// Split-bf16 MFMA GEMM: Y = X W^T + b.   (structure unchanged from R3)
// z=0 -> Qhi/Qlo bf16 [bh][T][64] (scaled by QSCALE)
// z=1 -> Khi/Klo bf16 [bh][T][64]
// z=2 -> V^T   fp16  [bh][64][T]
// ---------------------------------------------------------------------------
__global__ __launch_bounds__(256, 2) void qkv_gemm_mfma(
    const short* __restrict__ Xhi, const short* __restrict__ Xlo,
    const short* __restrict__ Wh3, const short* __restrict__ Wl3,  // [3][N][K]
    const float* __restrict__ bq, const float* __restrict__ bk,
    const float* __restrict__ bv,
    short* __restrict__ Qhi, short* __restrict__ Qlo,
    short* __restrict__ Khi, short* __restrict__ Klo,
    _Float16* __restrict__ VgT)
{
    const int z = blockIdx.z;
    const short* Wh = Wh3 + (size_t)z * DMODEL * DMODEL;
    const short* Wl = Wl3 + (size_t)z * DMODEL * DMODEL;
    const float* bias = (z == 0) ? bq : (z == 1) ? bk : bv;

    __shared__ __align__(16) short Ah[128 * 32];
    __shared__ __align__(16) short Al[128 * 32];
    __shared__ __align__(16) short Bh[128 * 32];
    __shared__ __align__(16) short Bl[128 * 32];

    const int tid  = threadIdx.x;
    const int w    = tid >> 6;
    const int lane = tid & 63;
    const int t    = lane & 15;
    const int quad = lane >> 4;
    const int wm   = w >> 1, wn = w & 1;
    const int bm   = blockIdx.y * 128;
    const int bn   = blockIdx.x * 128;

    const int r_local = lane >> 2;
    const int kq      = (lane & 3) ^ ((r_local >> 1) & 3);
    const int row0    = w * 32 + r_local;
    const int slotq   = (quad ^ ((t >> 1) & 3)) * 8;

    f32x4 acc[4][4];
    #pragma unroll
    for (int i = 0; i < 4; i++)
        #pragma unroll
        for (int j = 0; j < 4; j++) acc[i][j] = (f32x4){0.f, 0.f, 0.f, 0.f};

    for (int k0 = 0; k0 < DMODEL; k0 += 32) {
        __syncthreads();
        #pragma unroll
        for (int i = 0; i < 2; i++) {
            int row = row0 + i * 16;
            size_t ga = (size_t)(bm + row) * DMODEL + k0 + kq * 8;
            size_t gb = (size_t)(bn + row) * DMODEL + k0 + kq * 8;
            int ldst = (w * 32 + i * 16) * 32;
            async_copy16(&Ah[ldst], Xhi + ga);
            async_copy16(&Al[ldst], Xlo + ga);
            async_copy16(&Bh[ldst], Wh + gb);
            async_copy16(&Bl[ldst], Wl + gb);
        }
        __syncthreads();

        bf16x8 ah[4], al[4], bh[4], bl[4];
        #pragma unroll
        for (int mt = 0; mt < 4; mt++) {
            int off = (wm * 64 + mt * 16 + t) * 32 + slotq;
            ah[mt] = *(const bf16x8*)&Ah[off];
            al[mt] = *(const bf16x8*)&Al[off];
        }
        #pragma unroll
        for (int nt = 0; nt < 4; nt++) {
            int off = (wn * 64 + nt * 16 + t) * 32 + slotq;
            bh[nt] = *(const bf16x8*)&Bh[off];
            bl[nt] = *(const bf16x8*)&Bl[off];
        }
        #pragma unroll
        for (int mt = 0; mt < 4; mt++)
            #pragma unroll
            for (int nt = 0; nt < 4; nt++) {
                acc[mt][nt] = __builtin_amdgcn_mfma_f32_16x16x32_bf16(
                    al[mt], bh[nt], acc[mt][nt], 0, 0, 0);
                acc[mt][nt] = __builtin_amdgcn_mfma_f32_16x16x32_bf16(
                    ah[mt], bl[nt], acc[mt][nt], 0, 0, 0);
                acc[mt][nt] = __builtin_amdgcn_mfma_f32_16x16x32_bf16(
                    ah[mt], bh[nt], acc[mt][nt], 0, 0, 0);
            }
    }

    const float scale = (z == 0) ? QSCALE : 1.0f;
    const int n_base = bn + wn * 64;
    const int h_head = n_base >> 6;
    float bvs[4];
    #pragma unroll
    for (int nt = 0; nt < 4; nt++)
        bvs[nt] = bias[n_base + nt * 16 + t];

    #pragma unroll
    for (int mt = 0; mt < 4; mt++) {
        #pragma unroll
        for (int r = 0; r < 4; r++) {
            int m  = bm + wm * 64 + mt * 16 + quad * 4 + r;
            int b_ = m >> 11;
            int t_ = m & 2047;
            #pragma unroll
            for (int nt = 0; nt < 4; nt++) {
                int d = nt * 16 + t;
                float v = (acc[mt][nt][r] + bvs[nt]) * scale;
                if (z == 2) {
                    size_t idx = ((size_t)(b_ * NHEAD + h_head) * HDIM + d) * TSEQ + t_;
                    VgT[idx] = (_Float16)v;
                } else {
                    size_t idx = (((size_t)(b_ * NHEAD + h_head) * TSEQ + t_) << 6) + d;
                    short hb = f2bf(v);
                    short lb = f2bf(v - bf2f(hb));
                    if (z == 0) { Qhi[idx] = hb; Qlo[idx] = lb; }
                    else        { Khi[idx] = hb; Klo[idx] = lb; }
                }
            }
        }
    }
}

// ---------------------------------------------------------------------------
// MFMA flash attention v3.1 — pipelined async staging (R5 + swizzle-read fix).
//  - Staging stores global chunk g of row r at LDS slot g^(r&7); the read
//    offset is slot*8 with the dh half ENCODED IN THE SLOT (no +32!).
//    R5's "+32" for the dh=1 half read past the row end -> wrong data.
// LDS: 2*(8+8+8) KB + P 18 KB = 66 KB -> 2 blocks/CU.
// ---------------------------------------------------------------------------
__global__ __launch_bounds__(256, 2) void attn_fwd(
    const short* __restrict__ Qhi, const short* __restrict__ Qlo,
    const short* __restrict__ Khi, const short* __restrict__ Klo,
    const _Float16* __restrict__ VgT,   // [bh][64][T]
    float* __restrict__ out)            // [B][T][1024]
{
    __shared__ __align__(16) short    Kh_lds[2][64 * 64];
    __shared__ __align__(16) short    Kl_lds[2][64 * 64];
    __shared__ __align__(16) _Float16 Vt_lds[2][64 * 64];
    __shared__ __align__(16) _Float16 P_lds [128 * 72];

    const int tid  = threadIdx.x;
    const int qb   = 15 - blockIdx.x;      // heavy blocks first
    const int bh   = blockIdx.y;
    const int b    = bh >> 4, h = bh & 15;
    const int w    = tid >> 6;
    const int lane = tid & 63;
    const int t    = lane & 15;
    const int quad = lane >> 4;

    // staging geometry: per round, 256 lanes x 16B = 32 rows of 128B.
    // lane covers row rl = w*8 + (lane>>3), swizzled chunk (lane&7)^(rl&7).
    const int rl      = w * 8 + (lane >> 3);         // 0..31 within round
    const int chsw    = (lane & 7) ^ ((lane >> 3) & 7);
    const int ld_off  = (w * 8) * 64;                // wave-uniform LDS base (shorts)

    const size_t kbase = (size_t)bh * TSEQ;          // K rows
    const size_t vbase = (size_t)bh * HDIM;          // V^T rows

    // Q A-frags: rows qb*128 + w*32 + mt*16 + t
    bf16x8 qh[2][2], ql[2][2];
    #pragma unroll
    for (int mt = 0; mt < 2; mt++) {
        size_t qrow = kbase + qb * 128 + w * 32 + mt * 16 + t;
        #pragma unroll
        for (int dh = 0; dh < 2; dh++) {
            qh[mt][dh] = *(const bf16x8*)(Qhi + qrow * 64 + dh * 32 + quad * 8);
            ql[mt][dh] = *(const bf16x8*)(Qlo + qrow * 64 + dh * 32 + quad * 8);
        }
    }

    f16x8 ones;
    #pragma unroll
    for (int i = 0; i < 8; i++) ones[i] = (_Float16)1.0f;

    f32x4 O[2][4], Ol[2];
    #pragma unroll
    for (int mt = 0; mt < 2; mt++) {
        Ol[mt] = (f32x4){0.f, 0.f, 0.f, 0.f};
        #pragma unroll
        for (int j = 0; j < 4; j++) O[mt][j] = (f32x4){0.f, 0.f, 0.f, 0.f};
    }
    float m_st[2][4];
    #pragma unroll
    for (int mt = 0; mt < 2; mt++)
        #pragma unroll
        for (int r = 0; r < 4; r++) m_st[mt][r] = -1e30f;

    const int ktmax = 2 * qb + 1;

    // read-side swizzled chunk offsets (shorts): chunk g=dh*4+quad lives at
    // slot g^(row&7), row&7 == t&7; offset within row = slot*8 (NO dh*32!)
    const int rs0 = ((0 * 4 + quad) ^ (t & 7)) * 8;
    const int rs1 = ((1 * 4 + quad) ^ (t & 7)) * 8;

    // ---- stage tile kt into buffer bf (6 async issues/thread) ----
    auto stage = [&](int kt, int bf) {
        #pragma unroll
        for (int i = 0; i < 2; i++) {
            int row = i * 32 + rl;                       // 0..63
            const short* gk = Khi + (kbase + kt * 64 + row) * 64 + chsw * 8;
            async_copy16(&Kh_lds[bf][(i * 32) * 64 + ld_off], gk);
            const short* gl = Klo + (kbase + kt * 64 + row) * 64 + chsw * 8;
            async_copy16(&Kl_lds[bf][(i * 32) * 64 + ld_off], gl);
            const _Float16* gv = VgT + (vbase + row) * TSEQ + kt * 64 + chsw * 8;
            async_copy16(&Vt_lds[bf][(i * 32) * 64 + ld_off], gv);
        }
    };

    stage(0, 0);   // prologue

    for (int kt = 0; kt <= ktmax; kt++) {
        __syncthreads();   // drains tile-kt loads (issued a full tile ago)
        if (kt < ktmax) stage(kt + 1, (kt + 1) & 1);
        const int cb = kt & 1;

        // ---- per m-tile: QK^T, mask, online softmax, P write ----
        #pragma unroll
        for (int mt = 0; mt < 2; mt++) {
            f32x4 S[4];
            #pragma unroll
            for (int ct = 0; ct < 4; ct++) {
                S[ct] = (f32x4){0.f, 0.f, 0.f, 0.f};
                int rowoff = (ct * 16 + t) * 64;
                {
                    bf16x8 kh = *(const bf16x8*)&Kh_lds[cb][rowoff + rs0];
                    bf16x8 kl = *(const bf16x8*)&Kl_lds[cb][rowoff + rs0];
                    S[ct] = __builtin_amdgcn_mfma_f32_16x16x32_bf16(ql[mt][0], kh, S[ct], 0, 0, 0);
                    S[ct] = __builtin_amdgcn_mfma_f32_16x16x32_bf16(qh[mt][0], kl, S[ct], 0, 0, 0);
                    S[ct] = __builtin_amdgcn_mfma_f32_16x16x32_bf16(qh[mt][0], kh, S[ct], 0, 0, 0);
                }
                {
                    bf16x8 kh = *(const bf16x8*)&Kh_lds[cb][rowoff + rs1];
                    bf16x8 kl = *(const bf16x8*)&Kl_lds[cb][rowoff + rs1];
                    S[ct] = __builtin_amdgcn_mfma_f32_16x16x32_bf16(ql[mt][1], kh, S[ct], 0, 0, 0);
                    S[ct] = __builtin_amdgcn_mfma_f32_16x16x32_bf16(qh[mt][1], kl, S[ct], 0, 0, 0);
                    S[ct] = __builtin_amdgcn_mfma_f32_16x16x32_bf16(qh[mt][1], kh, S[ct], 0, 0, 0);
                }
            }

            if (kt >= 2 * qb) {   // diagonal super-columns: causal mask
                int cbase = (kt - 2 * qb) * 64;
                #pragma unroll
                for (int ct = 0; ct < 4; ct++) {
                    int col = cbase + ct * 16 + t;
                    #pragma unroll
                    for (int r = 0; r < 4; r++)
                        if (col > w * 32 + mt * 16 + quad * 4 + r) S[ct][r] = -1e30f;
                }
            }

            #pragma unroll
            for (int r = 0; r < 4; r++) {
                float mx = fmaxf(fmaxf(S[0][r], S[1][r]), fmaxf(S[2][r], S[3][r]));
                mx = fmaxf(mx, __shfl_xor(mx, 1, 64));
                mx = fmaxf(mx, __shfl_xor(mx, 2, 64));
                mx = fmaxf(mx, __shfl_xor(mx, 4, 64));
                mx = fmaxf(mx, __shfl_xor(mx, 8, 64));
                float mn = fmaxf(m_st[mt][r], mx);
                float al = exp2f(m_st[mt][r] - mn);
                m_st[mt][r] = mn;
                #pragma unroll
                for (int ct = 0; ct < 4; ct++)
                    S[ct][r] = exp2f(S[ct][r] - mn);
                Ol[mt][r] *= al;
                #pragma unroll
                for (int ct2 = 0; ct2 < 4; ct2++) O[mt][ct2][r] *= al;
            }

            // P: C-layout -> A-layout via wave-private LDS strip (fp16)
            #pragma unroll
            for (int ct = 0; ct < 4; ct++)
                #pragma unroll
                for (int r = 0; r < 4; r++)
                    P_lds[(w*32 + mt*16 + quad*4 + r) * 72 + ct*16 + t] =
                        (_Float16)S[ct][r];
        }

        // ---- PV + row-sum (fp16 MFMA); V frags read here, just in time ----
        #pragma unroll
        for (int mt = 0; mt < 2; mt++) {
            f16x8 p0 = *(const f16x8*)&P_lds[(w*32 + mt*16 + t)*72 + quad*8];
            f16x8 p1 = *(const f16x8*)&P_lds[(w*32 + mt*16 + t)*72 + 32 + quad*8];
            #pragma unroll
            for (int ct2 = 0; ct2 < 4; ct2++) {
                int rowoff = (ct2 * 16 + t) * 64;
                f16x8 v0 = *(const f16x8*)&Vt_lds[cb][rowoff + rs0];
                f16x8 v1 = *(const f16x8*)&Vt_lds[cb][rowoff + rs1];
                O[mt][ct2] = __builtin_amdgcn_mfma_f32_16x16x32_f16(p0, v0, O[mt][ct2], 0, 0, 0);
                O[mt][ct2] = __builtin_amdgcn_mfma_f32_16x16x32_f16(p1, v1, O[mt][ct2], 0, 0, 0);
            }
            Ol[mt] = __builtin_amdgcn_mfma_f32_16x16x32_f16(p0, ones, Ol[mt], 0, 0, 0);
            Ol[mt] = __builtin_amdgcn_mfma_f32_16x16x32_f16(p1, ones, Ol[mt], 0, 0, 0);
        }
    }

    // epilogue: normalize, write [B][T][H*64] fp32
    #pragma unroll
    for (int mt = 0; mt < 2; mt++) {
        float* ob = out + ((size_t)b * TSEQ + qb * 128 + w * 32 + mt * 16 + quad * 4) * DMODEL
                  + h * 64;
        #pragma unroll
        for (int r = 0; r < 4; r++) {
            float inv = 1.0f / Ol[mt][r];
            #pragma unroll
            for (int ct2 = 0; ct2 < 4; ct2++)
                ob[(size_t)r * DMODEL + ct2 * 16 + t] = O[mt][ct2][r] * inv;
        }
    }
}

// ---------------------------------------------------------------------------
extern "C" void kernel_launch(void* const* d_in, const int* in_sizes, int n_in,
                              void* d_out, int out_size, void* d_ws, size_t ws_size,
                              hipStream_t stream)
{
    const float* x  = (const float*)d_in[0];
    const float* Wq = (const float*)d_in[1];
    const float* bq = (const float*)d_in[2];
    const float* Wk = (const float*)d_in[3];
    const float* bk = (const float*)d_in[4];
    const float* Wv = (const float*)d_in[5];
    const float* bv = (const float*)d_in[6];

    const size_t TEN = (size_t)MROWS * DMODEL;   // 8M
    const size_t WEN = (size_t)DMODEL * DMODEL;  // 1M
    short* Xhi = (short*)d_ws;
    short* Xlo = Xhi + TEN;
    short* Whi = Xlo + TEN;
    short* Wlo = Whi + 3 * WEN;
    short* Qhi = Wlo + 3 * WEN;
    short* Qlo = Qhi + TEN;
    short* Khi = Qlo + TEN;
    short* Klo = Khi + TEN;
    _Float16* VgT = (_Float16*)(Klo + TEN);
    float* out = (float*)d_out;

    int nsplit = (X_F4 + 3 * W_F4) / 256;
    split_all<<<nsplit, 256, 0, stream>>>(x, Wq, Wk, Wv, Xhi, Xlo, Whi, Wlo);

    dim3 gg(DMODEL / 128, MROWS / 128, 3);
    qkv_gemm_mfma<<<gg, 256, 0, stream>>>(Xhi, Xlo, Whi, Wlo, bq, bk, bv,
                                          Qhi, Qlo, Khi, Klo, VgT);

    dim3 ga(TSEQ / 128, NBATCH * NHEAD);
    attn_fwd<<<ga, 256, 0, stream>>>(Qhi, Qlo, Khi, Klo, VgT, out);
}

// Round 7
// 468.252 us; speedup vs baseline: 1.5724x; 1.0967x over previous
//
#include <hip/hip_runtime.h>
#include <math.h>

#define TSEQ   2048
#define NBATCH 4
#define NHEAD  16
#define HDIM   64
#define DMODEL 1024
#define MROWS  (NBATCH * TSEQ)   // 8192
// fold 8 * log2(e) into Q so softmax runs in exp2 domain (v_exp_f32 native)
#define QSCALE 11.541560327111707f

typedef float f32x4  __attribute__((ext_vector_type(4)));
typedef short bf16x8 __attribute__((ext_vector_type(8)));
typedef _Float16 f16x8 __attribute__((ext_vector_type(8)));

static __device__ __forceinline__ short f2bf(float f) {  // RNE float->bf16
    union { float f; unsigned u; } a; a.f = f;
    unsigned r = a.u + 0x7FFFu + ((a.u >> 16) & 1u);
    return (short)(r >> 16);
}
static __device__ __forceinline__ float bf2f(short s) {
    union { unsigned u; float f; } a; a.u = ((unsigned)(unsigned short)s) << 16;
    return a.f;
}

// async global->LDS, 16B per lane; LDS dest = wave-uniform base + lane*16
static __device__ __forceinline__ void async_copy16(void* lds, const void* g) {
    __builtin_amdgcn_global_load_lds(
        (const __attribute__((address_space(1))) void*)g,
        (__attribute__((address_space(3))) void*)lds, 16, 0, 0);
}

// ---------------------------------------------------------------------------
// One fused fp32 -> (hi,lo) bf16 splitter for X, Wq, Wk, Wv.
// ---------------------------------------------------------------------------
#define X_F4 (MROWS * DMODEL / 4)          // 2097152
#define W_F4 (DMODEL * DMODEL / 4)         // 262144  (1<<18)
__global__ __launch_bounds__(256) void split_all(
    const float* __restrict__ x,
    const float* __restrict__ wq, const float* __restrict__ wk,
    const float* __restrict__ wv,
    short* __restrict__ Xhi, short* __restrict__ Xlo,
    short* __restrict__ Whi, short* __restrict__ Wlo)
{
    int gid = blockIdx.x * 256 + threadIdx.x;
    const float* src; short* dh; short* dl; int off;
    if (gid < X_F4) {
        src = x; dh = Xhi; dl = Xlo; off = gid;
    } else {
        int r = gid - X_F4;
        int z = r >> 18;                   // 0..2
        off = r & (W_F4 - 1);
        src = (z == 0) ? wq : (z == 1) ? wk : wv;
        dh = Whi + (size_t)z * DMODEL * DMODEL;
        dl = Wlo + (size_t)z * DMODEL * DMODEL;
    }
    float4 v = ((const float4*)src)[off];
    float f[4] = {v.x, v.y, v.z, v.w};
    short h[4], l[4];
    #pragma unroll
    for (int c = 0; c < 4; c++) {
        h[c] = f2bf(f[c]);
        l[c] = f2bf(f[c] - bf2f(h[c]));
    }
    *(float2*)(dh + (size_t)off * 4) = *(const float2*)h;
    *(float2*)(dl + (size_t)off * 4) = *(const float2*)l;
}

// ---------------------------------------------------------------------------
// Split-bf16 MFMA GEMM: Y = X W^T + b.
// z=0 -> Qhi/Qlo bf16 [bh][T][64] (scaled by QSCALE)   3-MFMA split
// z=1 -> Khi/Klo bf16 [bh][T][64]                      3-MFMA split
// z=2 -> V^T   fp16  [bh][64][T]   single bf16 MFMA (V only feeds fp16 PV;
//        bf16 product noise ~2e-3 abs — irrelevant vs 0.1 threshold)
// ---------------------------------------------------------------------------
__global__ __launch_bounds__(256, 2) void qkv_gemm_mfma(
    const short* __restrict__ Xhi, const short* __restrict__ Xlo,
    const short* __restrict__ Wh3, const short* __restrict__ Wl3,  // [3][N][K]
    const float* __restrict__ bq, const float* __restrict__ bk,
    const float* __restrict__ bv,
    short* __restrict__ Qhi, short* __restrict__ Qlo,
    short* __restrict__ Khi, short* __restrict__ Klo,
    _Float16* __restrict__ VgT)
{
    const int z = blockIdx.z;
    const bool dolo = (z != 2);
    const short* Wh = Wh3 + (size_t)z * DMODEL * DMODEL;
    const short* Wl = Wl3 + (size_t)z * DMODEL * DMODEL;
    const float* bias = (z == 0) ? bq : (z == 1) ? bk : bv;

    __shared__ __align__(16) short Ah[128 * 32];
    __shared__ __align__(16) short Al[128 * 32];
    __shared__ __align__(16) short Bh[128 * 32];
    __shared__ __align__(16) short Bl[128 * 32];

    const int tid  = threadIdx.x;
    const int w    = tid >> 6;
    const int lane = tid & 63;
    const int t    = lane & 15;
    const int quad = lane >> 4;
    const int wm   = w >> 1, wn = w & 1;
    const int bm   = blockIdx.y * 128;
    const int bn   = blockIdx.x * 128;

    const int r_local = lane >> 2;
    const int kq      = (lane & 3) ^ ((r_local >> 1) & 3);
    const int row0    = w * 32 + r_local;
    const int slotq   = (quad ^ ((t >> 1) & 3)) * 8;

    f32x4 acc[4][4];
    #pragma unroll
    for (int i = 0; i < 4; i++)
        #pragma unroll
        for (int j = 0; j < 4; j++) acc[i][j] = (f32x4){0.f, 0.f, 0.f, 0.f};

    for (int k0 = 0; k0 < DMODEL; k0 += 32) {
        __syncthreads();
        #pragma unroll
        for (int i = 0; i < 2; i++) {
            int row = row0 + i * 16;
            size_t ga = (size_t)(bm + row) * DMODEL + k0 + kq * 8;
            size_t gb = (size_t)(bn + row) * DMODEL + k0 + kq * 8;
            int ldst = (w * 32 + i * 16) * 32;
            async_copy16(&Ah[ldst], Xhi + ga);
            async_copy16(&Bh[ldst], Wh + gb);
            if (dolo) {
                async_copy16(&Al[ldst], Xlo + ga);
                async_copy16(&Bl[ldst], Wl + gb);
            }
        }
        __syncthreads();

        bf16x8 ah[4], al[4], bh[4], bl[4];
        #pragma unroll
        for (int mt = 0; mt < 4; mt++) {
            int off = (wm * 64 + mt * 16 + t) * 32 + slotq;
            ah[mt] = *(const bf16x8*)&Ah[off];
            if (dolo) al[mt] = *(const bf16x8*)&Al[off];
        }
        #pragma unroll
        for (int nt = 0; nt < 4; nt++) {
            int off = (wn * 64 + nt * 16 + t) * 32 + slotq;
            bh[nt] = *(const bf16x8*)&Bh[off];
            if (dolo) bl[nt] = *(const bf16x8*)&Bl[off];
        }
        #pragma unroll
        for (int mt = 0; mt < 4; mt++)
            #pragma unroll
            for (int nt = 0; nt < 4; nt++) {
                if (dolo) {
                    acc[mt][nt] = __builtin_amdgcn_mfma_f32_16x16x32_bf16(
                        al[mt], bh[nt], acc[mt][nt], 0, 0, 0);
                    acc[mt][nt] = __builtin_amdgcn_mfma_f32_16x16x32_bf16(
                        ah[mt], bl[nt], acc[mt][nt], 0, 0, 0);
                }
                acc[mt][nt] = __builtin_amdgcn_mfma_f32_16x16x32_bf16(
                    ah[mt], bh[nt], acc[mt][nt], 0, 0, 0);
            }
    }

    const float scale = (z == 0) ? QSCALE : 1.0f;
    const int n_base = bn + wn * 64;
    const int h_head = n_base >> 6;
    float bvs[4];
    #pragma unroll
    for (int nt = 0; nt < 4; nt++)
        bvs[nt] = bias[n_base + nt * 16 + t];

    #pragma unroll
    for (int mt = 0; mt < 4; mt++) {
        #pragma unroll
        for (int r = 0; r < 4; r++) {
            int m  = bm + wm * 64 + mt * 16 + quad * 4 + r;
            int b_ = m >> 11;
            int t_ = m & 2047;
            #pragma unroll
            for (int nt = 0; nt < 4; nt++) {
                int d = nt * 16 + t;
                float v = (acc[mt][nt][r] + bvs[nt]) * scale;
                if (z == 2) {
                    size_t idx = ((size_t)(b_ * NHEAD + h_head) * HDIM + d) * TSEQ + t_;
                    VgT[idx] = (_Float16)v;
                } else {
                    size_t idx = (((size_t)(b_ * NHEAD + h_head) * TSEQ + t_) << 6) + d;
                    short hb = f2bf(v);
                    short lb = f2bf(v - bf2f(hb));
                    if (z == 0) { Qhi[idx] = hb; Qlo[idx] = lb; }
                    else        { Khi[idx] = hb; Klo[idx] = lb; }
                }
            }
        }
    }
}

// ---------------------------------------------------------------------------
// MFMA flash attention v4 — pair-batched softmax.
//  - Per iteration: stage TWO 64-col K/V tiles (both buffers), one drain
//    barrier, compute S over all 128 cols, ONE max-reduce/rescale pass
//    (halves shuffle chains, alpha exp2s, O rescales per column).
//  - alpha-skip: if no lane's row-max grew (ballot), skip rescale entirely.
//  - PV in two 64-col halves reusing the P strip (same-wave in-order DS
//    makes the WAR on the strip safe).
//  - 2 barriers per pair, no cross-pair prefetch: with 2 blocks/CU the other
//    block's compute covers the drain (m114 implicit overlap).
// LDS: 2*(8+8+8) + 18 = 66 KB -> 2 blocks/CU.
// ---------------------------------------------------------------------------
__global__ __launch_bounds__(256, 2) void attn_fwd(
    const short* __restrict__ Qhi, const short* __restrict__ Qlo,
    const short* __restrict__ Khi, const short* __restrict__ Klo,
    const _Float16* __restrict__ VgT,   // [bh][64][T]
    float* __restrict__ out)            // [B][T][1024]
{
    __shared__ __align__(16) short    Kh_lds[2][64 * 64];
    __shared__ __align__(16) short    Kl_lds[2][64 * 64];
    __shared__ __align__(16) _Float16 Vt_lds[2][64 * 64];
    __shared__ __align__(16) _Float16 P_lds [128 * 72];

    const int tid  = threadIdx.x;
    const int qb   = 15 - blockIdx.x;      // heavy blocks first
    const int bh   = blockIdx.y;
    const int b    = bh >> 4, h = bh & 15;
    const int w    = tid >> 6;
    const int lane = tid & 63;
    const int t    = lane & 15;
    const int quad = lane >> 4;

    // staging geometry: per round, 256 lanes x 16B = 32 rows of 128B.
    const int rl      = w * 8 + (lane >> 3);         // 0..31 within round
    const int chsw    = (lane & 7) ^ ((lane >> 3) & 7);
    const int ld_off  = (w * 8) * 64;                // wave-uniform LDS base

    const size_t kbase = (size_t)bh * TSEQ;          // K rows
    const size_t vbase = (size_t)bh * HDIM;          // V^T rows

    // Q A-frags
    bf16x8 qh[2][2], ql[2][2];
    #pragma unroll
    for (int mt = 0; mt < 2; mt++) {
        size_t qrow = kbase + qb * 128 + w * 32 + mt * 16 + t;
        #pragma unroll
        for (int dh = 0; dh < 2; dh++) {
            qh[mt][dh] = *(const bf16x8*)(Qhi + qrow * 64 + dh * 32 + quad * 8);
            ql[mt][dh] = *(const bf16x8*)(Qlo + qrow * 64 + dh * 32 + quad * 8);
        }
    }

    f16x8 ones;
    #pragma unroll
    for (int i = 0; i < 8; i++) ones[i] = (_Float16)1.0f;

    f32x4 O[2][4], Ol[2];
    #pragma unroll
    for (int mt = 0; mt < 2; mt++) {
        Ol[mt] = (f32x4){0.f, 0.f, 0.f, 0.f};
        #pragma unroll
        for (int j = 0; j < 4; j++) O[mt][j] = (f32x4){0.f, 0.f, 0.f, 0.f};
    }
    float m_st[2][4];
    #pragma unroll
    for (int mt = 0; mt < 2; mt++)
        #pragma unroll
        for (int r = 0; r < 4; r++) m_st[mt][r] = -1e30f;

    // read-side swizzled chunk offsets: chunk g=dh*4+quad at slot g^(t&7)
    const int rs0 = ((0 * 4 + quad) ^ (t & 7)) * 8;
    const int rs1 = ((1 * 4 + quad) ^ (t & 7)) * 8;

    auto stage = [&](int kt, int bf) {
        #pragma unroll
        for (int i = 0; i < 2; i++) {
            int row = i * 32 + rl;
            const short* gk = Khi + (kbase + kt * 64 + row) * 64 + chsw * 8;
            async_copy16(&Kh_lds[bf][(i * 32) * 64 + ld_off], gk);
            const short* gl = Klo + (kbase + kt * 64 + row) * 64 + chsw * 8;
            async_copy16(&Kl_lds[bf][(i * 32) * 64 + ld_off], gl);
            const _Float16* gv = VgT + (vbase + row) * TSEQ + kt * 64 + chsw * 8;
            async_copy16(&Vt_lds[bf][(i * 32) * 64 + ld_off], gv);
        }
    };

    const int npair = qb + 1;

    for (int p = 0; p < npair; p++) {
        __syncthreads();              // previous pair's LDS reads complete
        stage(2 * p, 0);
        stage(2 * p + 1, 1);
        __syncthreads();              // drain the 12 async copies

        #pragma unroll
        for (int mt = 0; mt < 2; mt++) {
            // ---- S over 128 cols: c8=0..3 from buf0, 4..7 from buf1 ----
            f32x4 S[8];
            #pragma unroll
            for (int c8 = 0; c8 < 8; c8++) {
                S[c8] = (f32x4){0.f, 0.f, 0.f, 0.f};
                const int bf = c8 >> 2;
                const int rowoff = ((c8 & 3) * 16 + t) * 64;
                {
                    bf16x8 kh = *(const bf16x8*)&Kh_lds[bf][rowoff + rs0];
                    bf16x8 kl = *(const bf16x8*)&Kl_lds[bf][rowoff + rs0];
                    S[c8] = __builtin_amdgcn_mfma_f32_16x16x32_bf16(ql[mt][0], kh, S[c8], 0, 0, 0);
                    S[c8] = __builtin_amdgcn_mfma_f32_16x16x32_bf16(qh[mt][0], kl, S[c8], 0, 0, 0);
                    S[c8] = __builtin_amdgcn_mfma_f32_16x16x32_bf16(qh[mt][0], kh, S[c8], 0, 0, 0);
                }
                {
                    bf16x8 kh = *(const bf16x8*)&Kh_lds[bf][rowoff + rs1];
                    bf16x8 kl = *(const bf16x8*)&Kl_lds[bf][rowoff + rs1];
                    S[c8] = __builtin_amdgcn_mfma_f32_16x16x32_bf16(ql[mt][1], kh, S[c8], 0, 0, 0);
                    S[c8] = __builtin_amdgcn_mfma_f32_16x16x32_bf16(qh[mt][1], kl, S[c8], 0, 0, 0);
                    S[c8] = __builtin_amdgcn_mfma_f32_16x16x32_bf16(qh[mt][1], kh, S[c8], 0, 0, 0);
                }
            }

            // causal mask (only the last pair contains the diagonal)
            if (p == qb) {
                #pragma unroll
                for (int c8 = 0; c8 < 8; c8++) {
                    int col = c8 * 16 + t;
                    #pragma unroll
                    for (int r = 0; r < 4; r++)
                        if (col > w * 32 + mt * 16 + quad * 4 + r) S[c8][r] = -1e30f;
                }
            }

            // ---- ONE max-reduce + (conditional) rescale per 128 cols ----
            float mx[4]; bool grow = false;
            #pragma unroll
            for (int r = 0; r < 4; r++) {
                float a0 = fmaxf(fmaxf(S[0][r], S[1][r]), fmaxf(S[2][r], S[3][r]));
                float a1 = fmaxf(fmaxf(S[4][r], S[5][r]), fmaxf(S[6][r], S[7][r]));
                float v = fmaxf(a0, a1);
                v = fmaxf(v, __shfl_xor(v, 1, 64));
                v = fmaxf(v, __shfl_xor(v, 2, 64));
                v = fmaxf(v, __shfl_xor(v, 4, 64));
                v = fmaxf(v, __shfl_xor(v, 8, 64));
                mx[r] = v;
                grow = grow || (v > m_st[mt][r]);
            }
            if (__ballot(grow)) {
                #pragma unroll
                for (int r = 0; r < 4; r++) {
                    float mn = fmaxf(m_st[mt][r], mx[r]);
                    float al = exp2f(m_st[mt][r] - mn);
                    m_st[mt][r] = mn;
                    Ol[mt][r] *= al;
                    #pragma unroll
                    for (int ct2 = 0; ct2 < 4; ct2++) O[mt][ct2][r] *= al;
                }
            }
            #pragma unroll
            for (int c8 = 0; c8 < 8; c8++)
                #pragma unroll
                for (int r = 0; r < 4; r++)
                    S[c8][r] = exp2f(S[c8][r] - m_st[mt][r]);

            // ---- PV in two halves, reusing the wave-private P strip ----
            const int prow = w * 32 + mt * 16;
            #pragma unroll
            for (int half = 0; half < 2; half++) {
                #pragma unroll
                for (int ct = 0; ct < 4; ct++)
                    #pragma unroll
                    for (int r = 0; r < 4; r++)
                        P_lds[(prow + quad * 4 + r) * 72 + ct * 16 + t] =
                            (_Float16)S[half * 4 + ct][r];
                f16x8 p0 = *(const f16x8*)&P_lds[(prow + t) * 72 + quad * 8];
                f16x8 p1 = *(const f16x8*)&P_lds[(prow + t) * 72 + 32 + quad * 8];
                #pragma unroll
                for (int ct2 = 0; ct2 < 4; ct2++) {
                    int rowoff2 = (ct2 * 16 + t) * 64;
                    f16x8 v0 = *(const f16x8*)&Vt_lds[half][rowoff2 + rs0];
                    f16x8 v1 = *(const f16x8*)&Vt_lds[half][rowoff2 + rs1];
                    O[mt][ct2] = __builtin_amdgcn_mfma_f32_16x16x32_f16(p0, v0, O[mt][ct2], 0, 0, 0);
                    O[mt][ct2] = __builtin_amdgcn_mfma_f32_16x16x32_f16(p1, v1, O[mt][ct2], 0, 0, 0);
                }
                Ol[mt] = __builtin_amdgcn_mfma_f32_16x16x32_f16(p0, ones, Ol[mt], 0, 0, 0);
                Ol[mt] = __builtin_amdgcn_mfma_f32_16x16x32_f16(p1, ones, Ol[mt], 0, 0, 0);
            }
        }
    }

    // epilogue: normalize, write [B][T][H*64] fp32
    #pragma unroll
    for (int mt = 0; mt < 2; mt++) {
        float* ob = out + ((size_t)b * TSEQ + qb * 128 + w * 32 + mt * 16 + quad * 4) * DMODEL
                  + h * 64;
        #pragma unroll
        for (int r = 0; r < 4; r++) {
            float inv = 1.0f / Ol[mt][r];
            #pragma unroll
            for (int ct2 = 0; ct2 < 4; ct2++)
                ob[(size_t)r * DMODEL + ct2 * 16 + t] = O[mt][ct2][r] * inv;
        }
    }
}

// ---------------------------------------------------------------------------
extern "C" void kernel_launch(void* const* d_in, const int* in_sizes, int n_in,
                              void* d_out, int out_size, void* d_ws, size_t ws_size,
                              hipStream_t stream)
{
    const float* x  = (const float*)d_in[0];
    const float* Wq = (const float*)d_in[1];
    const float* bq = (const float*)d_in[2];
    const float* Wk = (const float*)d_in[3];
    const float* bk = (const float*)d_in[4];
    const float* Wv = (const float*)d_in[5];
    const float* bv = (const float*)d_in[6];

    const size_t TEN = (size_t)MROWS * DMODEL;   // 8M
    const size_t WEN = (size_t)DMODEL * DMODEL;  // 1M
    short* Xhi = (short*)d_ws;
    short* Xlo = Xhi + TEN;
    short* Whi = Xlo + TEN;
    short* Wlo = Whi + 3 * WEN;
    short* Qhi = Wlo + 3 * WEN;
    short* Qlo = Qhi + TEN;
    short* Khi = Qlo + TEN;
    short* Klo = Khi + TEN;
    _Float16* VgT = (_Float16*)(Klo + TEN);
    float* out = (float*)d_out;

    int nsplit = (X_F4 + 3 * W_F4) / 256;
    split_all<<<nsplit, 256, 0, stream>>>(x, Wq, Wk, Wv, Xhi, Xlo, Whi, Wlo);

    dim3 gg(DMODEL / 128, MROWS / 128, 3);
    qkv_gemm_mfma<<<gg, 256, 0, stream>>>(Xhi, Xlo, Whi, Wlo, bq, bk, bv,
                                          Qhi, Qlo, Khi, Klo, VgT);

    dim3 ga(TSEQ / 128, NBATCH * NHEAD);
    attn_fwd<<<ga, 256, 0, stream>>>(Qhi, Qlo, Khi, Klo, VgT, out);
}

// Round 8
// 376.382 us; speedup vs baseline: 1.9562x; 1.2441x over previous
//
#include <hip/hip_runtime.h>
#include <math.h>

#define TSEQ   2048
#define NBATCH 4
#define NHEAD  16
#define HDIM   64
#define DMODEL 1024
#define MROWS  (NBATCH * TSEQ)   // 8192
// fold 8 * log2(e) into Q so softmax runs in exp2 domain (v_exp_f32 native)
#define QSCALE 11.541560327111707f

typedef float f32x4  __attribute__((ext_vector_type(4)));
typedef short bf16x8 __attribute__((ext_vector_type(8)));
typedef _Float16 f16x8 __attribute__((ext_vector_type(8)));

static __device__ __forceinline__ short f2bf(float f) {  // RNE float->bf16
    union { float f; unsigned u; } a; a.f = f;
    unsigned r = a.u + 0x7FFFu + ((a.u >> 16) & 1u);
    return (short)(r >> 16);
}
static __device__ __forceinline__ float bf2f(short s) {
    union { unsigned u; float f; } a; a.u = ((unsigned)(unsigned short)s) << 16;
    return a.f;
}

// async global->LDS, 16B per lane; LDS dest = wave-uniform base + lane*16
static __device__ __forceinline__ void async_copy16(void* lds, const void* g) {
    __builtin_amdgcn_global_load_lds(
        (const __attribute__((address_space(1))) void*)g,
        (__attribute__((address_space(3))) void*)lds, 16, 0, 0);
}

// ---------------------------------------------------------------------------
// One fused fp32 -> (hi,lo) bf16 splitter for X, Wq, Wk, Wv.
// ---------------------------------------------------------------------------
#define X_F4 (MROWS * DMODEL / 4)          // 2097152
#define W_F4 (DMODEL * DMODEL / 4)         // 262144  (1<<18)
__global__ __launch_bounds__(256) void split_all(
    const float* __restrict__ x,
    const float* __restrict__ wq, const float* __restrict__ wk,
    const float* __restrict__ wv,
    short* __restrict__ Xhi, short* __restrict__ Xlo,
    short* __restrict__ Whi, short* __restrict__ Wlo)
{
    int gid = blockIdx.x * 256 + threadIdx.x;
    const float* src; short* dh; short* dl; int off;
    if (gid < X_F4) {
        src = x; dh = Xhi; dl = Xlo; off = gid;
    } else {
        int r = gid - X_F4;
        int z = r >> 18;                   // 0..2
        off = r & (W_F4 - 1);
        src = (z == 0) ? wq : (z == 1) ? wk : wv;
        dh = Whi + (size_t)z * DMODEL * DMODEL;
        dl = Wlo + (size_t)z * DMODEL * DMODEL;
    }
    float4 v = ((const float4*)src)[off];
    float f[4] = {v.x, v.y, v.z, v.w};
    short h[4], l[4];
    #pragma unroll
    for (int c = 0; c < 4; c++) {
        h[c] = f2bf(f[c]);
        l[c] = f2bf(f[c] - bf2f(h[c]));
    }
    *(float2*)(dh + (size_t)off * 4) = *(const float2*)h;
    *(float2*)(dl + (size_t)off * 4) = *(const float2*)l;
}

// ---------------------------------------------------------------------------
// Split-bf16 MFMA GEMM: Y = X W^T + b.
// z=0 -> Qhi/Qlo bf16 [bh][T][64] (scaled by QSCALE)   3-MFMA split
// z=1 -> Khi/Klo bf16 [bh][T][64]                      3-MFMA split
// z=2 -> V^T   fp16  [bh][64][T]   single bf16 MFMA
// ---------------------------------------------------------------------------
__global__ __launch_bounds__(256, 2) void qkv_gemm_mfma(
    const short* __restrict__ Xhi, const short* __restrict__ Xlo,
    const short* __restrict__ Wh3, const short* __restrict__ Wl3,  // [3][N][K]
    const float* __restrict__ bq, const float* __restrict__ bk,
    const float* __restrict__ bv,
    short* __restrict__ Qhi, short* __restrict__ Qlo,
    short* __restrict__ Khi, short* __restrict__ Klo,
    _Float16* __restrict__ VgT)
{
    const int z = blockIdx.z;
    const bool dolo = (z != 2);
    const short* Wh = Wh3 + (size_t)z * DMODEL * DMODEL;
    const short* Wl = Wl3 + (size_t)z * DMODEL * DMODEL;
    const float* bias = (z == 0) ? bq : (z == 1) ? bk : bv;

    __shared__ __align__(16) short Ah[128 * 32];
    __shared__ __align__(16) short Al[128 * 32];
    __shared__ __align__(16) short Bh[128 * 32];
    __shared__ __align__(16) short Bl[128 * 32];

    const int tid  = threadIdx.x;
    const int w    = tid >> 6;
    const int lane = tid & 63;
    const int t    = lane & 15;
    const int quad = lane >> 4;
    const int wm   = w >> 1, wn = w & 1;
    const int bm   = blockIdx.y * 128;
    const int bn   = blockIdx.x * 128;

    const int r_local = lane >> 2;
    const int kq      = (lane & 3) ^ ((r_local >> 1) & 3);
    const int row0    = w * 32 + r_local;
    const int slotq   = (quad ^ ((t >> 1) & 3)) * 8;

    f32x4 acc[4][4];
    #pragma unroll
    for (int i = 0; i < 4; i++)
        #pragma unroll
        for (int j = 0; j < 4; j++) acc[i][j] = (f32x4){0.f, 0.f, 0.f, 0.f};

    for (int k0 = 0; k0 < DMODEL; k0 += 32) {
        __syncthreads();
        #pragma unroll
        for (int i = 0; i < 2; i++) {
            int row = row0 + i * 16;
            size_t ga = (size_t)(bm + row) * DMODEL + k0 + kq * 8;
            size_t gb = (size_t)(bn + row) * DMODEL + k0 + kq * 8;
            int ldst = (w * 32 + i * 16) * 32;
            async_copy16(&Ah[ldst], Xhi + ga);
            async_copy16(&Bh[ldst], Wh + gb);
            if (dolo) {
                async_copy16(&Al[ldst], Xlo + ga);
                async_copy16(&Bl[ldst], Wl + gb);
            }
        }
        __syncthreads();

        bf16x8 ah[4], al[4], bh[4], bl[4];
        #pragma unroll
        for (int mt = 0; mt < 4; mt++) {
            int off = (wm * 64 + mt * 16 + t) * 32 + slotq;
            ah[mt] = *(const bf16x8*)&Ah[off];
            if (dolo) al[mt] = *(const bf16x8*)&Al[off];
        }
        #pragma unroll
        for (int nt = 0; nt < 4; nt++) {
            int off = (wn * 64 + nt * 16 + t) * 32 + slotq;
            bh[nt] = *(const bf16x8*)&Bh[off];
            if (dolo) bl[nt] = *(const bf16x8*)&Bl[off];
        }
        #pragma unroll
        for (int mt = 0; mt < 4; mt++)
            #pragma unroll
            for (int nt = 0; nt < 4; nt++) {
                if (dolo) {
                    acc[mt][nt] = __builtin_amdgcn_mfma_f32_16x16x32_bf16(
                        al[mt], bh[nt], acc[mt][nt], 0, 0, 0);
                    acc[mt][nt] = __builtin_amdgcn_mfma_f32_16x16x32_bf16(
                        ah[mt], bl[nt], acc[mt][nt], 0, 0, 0);
                }
                acc[mt][nt] = __builtin_amdgcn_mfma_f32_16x16x32_bf16(
                    ah[mt], bh[nt], acc[mt][nt], 0, 0, 0);
            }
    }

    const float scale = (z == 0) ? QSCALE : 1.0f;
    const int n_base = bn + wn * 64;
    const int h_head = n_base >> 6;
    float bvs[4];
    #pragma unroll
    for (int nt = 0; nt < 4; nt++)
        bvs[nt] = bias[n_base + nt * 16 + t];

    #pragma unroll
    for (int mt = 0; mt < 4; mt++) {
        #pragma unroll
        for (int r = 0; r < 4; r++) {
            int m  = bm + wm * 64 + mt * 16 + quad * 4 + r;
            int b_ = m >> 11;
            int t_ = m & 2047;
            #pragma unroll
            for (int nt = 0; nt < 4; nt++) {
                int d = nt * 16 + t;
                float v = (acc[mt][nt][r] + bvs[nt]) * scale;
                if (z == 2) {
                    size_t idx = ((size_t)(b_ * NHEAD + h_head) * HDIM + d) * TSEQ + t_;
                    VgT[idx] = (_Float16)v;
                } else {
                    size_t idx = (((size_t)(b_ * NHEAD + h_head) * TSEQ + t_) << 6) + d;
                    short hb = f2bf(v);
                    short lb = f2bf(v - bf2f(hb));
                    if (z == 0) { Qhi[idx] = hb; Qlo[idx] = lb; }
                    else        { Khi[idx] = hb; Klo[idx] = lb; }
                }
            }
        }
    }
}

// ---------------------------------------------------------------------------
// MFMA flash attention v5 — pair-batched softmax + BALANCED GRID.
//  Block (i, bh), i in [0,8): processes Q-tile i (i+1 pairs) then Q-tile
//  15-i (16-i pairs) -> every block does exactly 17 pair-units.
//  Grid 8x64 = 512 blocks = exactly 2/CU co-resident: no triangular tail,
//  time-avg occupancy pinned at the LDS cap.
// LDS: 2*(8+8+8) + 18 = 66 KB -> 2 blocks/CU.
// ---------------------------------------------------------------------------
__global__ __launch_bounds__(256, 2) void attn_fwd(
    const short* __restrict__ Qhi, const short* __restrict__ Qlo,
    const short* __restrict__ Khi, const short* __restrict__ Klo,
    const _Float16* __restrict__ VgT,   // [bh][64][T]
    float* __restrict__ out)            // [B][T][1024]
{
    __shared__ __align__(16) short    Kh_lds[2][64 * 64];
    __shared__ __align__(16) short    Kl_lds[2][64 * 64];
    __shared__ __align__(16) _Float16 Vt_lds[2][64 * 64];
    __shared__ __align__(16) _Float16 P_lds [128 * 72];

    const int tid  = threadIdx.x;
    const int bh   = blockIdx.y;
    const int b    = bh >> 4, h = bh & 15;
    const int w    = tid >> 6;
    const int lane = tid & 63;
    const int t    = lane & 15;
    const int quad = lane >> 4;

    // staging geometry: per round, 256 lanes x 16B = 32 rows of 128B.
    const int rl      = w * 8 + (lane >> 3);         // 0..31 within round
    const int chsw    = (lane & 7) ^ ((lane >> 3) & 7);
    const int ld_off  = (w * 8) * 64;                // wave-uniform LDS base

    const size_t kbase = (size_t)bh * TSEQ;          // K rows
    const size_t vbase = (size_t)bh * HDIM;          // V^T rows

    // read-side swizzled chunk offsets: chunk g=dh*4+quad at slot g^(t&7)
    const int rs0 = ((0 * 4 + quad) ^ (t & 7)) * 8;
    const int rs1 = ((1 * 4 + quad) ^ (t & 7)) * 8;

    f16x8 ones;
    #pragma unroll
    for (int i = 0; i < 8; i++) ones[i] = (_Float16)1.0f;

    auto stage = [&](int kt, int bf) {
        #pragma unroll
        for (int i = 0; i < 2; i++) {
            int row = i * 32 + rl;
            const short* gk = Khi + (kbase + kt * 64 + row) * 64 + chsw * 8;
            async_copy16(&Kh_lds[bf][(i * 32) * 64 + ld_off], gk);
            const short* gl = Klo + (kbase + kt * 64 + row) * 64 + chsw * 8;
            async_copy16(&Kl_lds[bf][(i * 32) * 64 + ld_off], gl);
            const _Float16* gv = VgT + (vbase + row) * TSEQ + kt * 64 + chsw * 8;
            async_copy16(&Vt_lds[bf][(i * 32) * 64 + ld_off], gv);
        }
    };

    // two complementary Q-tile segments: i+1 pairs, then 16-i pairs (17 total)
    #pragma unroll 1
    for (int seg = 0; seg < 2; seg++) {
        const int qb = seg ? (15 - blockIdx.x) : blockIdx.x;

        // Q A-frags for this segment
        bf16x8 qh[2][2], ql[2][2];
        #pragma unroll
        for (int mt = 0; mt < 2; mt++) {
            size_t qrow = kbase + qb * 128 + w * 32 + mt * 16 + t;
            #pragma unroll
            for (int dh = 0; dh < 2; dh++) {
                qh[mt][dh] = *(const bf16x8*)(Qhi + qrow * 64 + dh * 32 + quad * 8);
                ql[mt][dh] = *(const bf16x8*)(Qlo + qrow * 64 + dh * 32 + quad * 8);
            }
        }

        f32x4 O[2][4], Ol[2];
        #pragma unroll
        for (int mt = 0; mt < 2; mt++) {
            Ol[mt] = (f32x4){0.f, 0.f, 0.f, 0.f};
            #pragma unroll
            for (int j = 0; j < 4; j++) O[mt][j] = (f32x4){0.f, 0.f, 0.f, 0.f};
        }
        float m_st[2][4];
        #pragma unroll
        for (int mt = 0; mt < 2; mt++)
            #pragma unroll
            for (int r = 0; r < 4; r++) m_st[mt][r] = -1e30f;

        const int npair = qb + 1;

        #pragma unroll 1
        for (int p = 0; p < npair; p++) {
            __syncthreads();              // previous pair's LDS reads complete
            stage(2 * p, 0);
            stage(2 * p + 1, 1);
            __syncthreads();              // drain the 12 async copies

            #pragma unroll
            for (int mt = 0; mt < 2; mt++) {
                // ---- S over 128 cols: c8=0..3 from buf0, 4..7 from buf1 ----
                f32x4 S[8];
                #pragma unroll
                for (int c8 = 0; c8 < 8; c8++) {
                    S[c8] = (f32x4){0.f, 0.f, 0.f, 0.f};
                    const int bf = c8 >> 2;
                    const int rowoff = ((c8 & 3) * 16 + t) * 64;
                    {
                        bf16x8 kh = *(const bf16x8*)&Kh_lds[bf][rowoff + rs0];
                        bf16x8 kl = *(const bf16x8*)&Kl_lds[bf][rowoff + rs0];
                        S[c8] = __builtin_amdgcn_mfma_f32_16x16x32_bf16(ql[mt][0], kh, S[c8], 0, 0, 0);
                        S[c8] = __builtin_amdgcn_mfma_f32_16x16x32_bf16(qh[mt][0], kl, S[c8], 0, 0, 0);
                        S[c8] = __builtin_amdgcn_mfma_f32_16x16x32_bf16(qh[mt][0], kh, S[c8], 0, 0, 0);
                    }
                    {
                        bf16x8 kh = *(const bf16x8*)&Kh_lds[bf][rowoff + rs1];
                        bf16x8 kl = *(const bf16x8*)&Kl_lds[bf][rowoff + rs1];
                        S[c8] = __builtin_amdgcn_mfma_f32_16x16x32_bf16(ql[mt][1], kh, S[c8], 0, 0, 0);
                        S[c8] = __builtin_amdgcn_mfma_f32_16x16x32_bf16(qh[mt][1], kl, S[c8], 0, 0, 0);
                        S[c8] = __builtin_amdgcn_mfma_f32_16x16x32_bf16(qh[mt][1], kh, S[c8], 0, 0, 0);
                    }
                }

                // causal mask (only the last pair contains the diagonal)
                if (p == qb) {
                    #pragma unroll
                    for (int c8 = 0; c8 < 8; c8++) {
                        int col = c8 * 16 + t;
                        #pragma unroll
                        for (int r = 0; r < 4; r++)
                            if (col > w * 32 + mt * 16 + quad * 4 + r) S[c8][r] = -1e30f;
                    }
                }

                // ---- ONE max-reduce + (conditional) rescale per 128 cols ----
                float mx[4]; bool grow = false;
                #pragma unroll
                for (int r = 0; r < 4; r++) {
                    float a0 = fmaxf(fmaxf(S[0][r], S[1][r]), fmaxf(S[2][r], S[3][r]));
                    float a1 = fmaxf(fmaxf(S[4][r], S[5][r]), fmaxf(S[6][r], S[7][r]));
                    float v = fmaxf(a0, a1);
                    v = fmaxf(v, __shfl_xor(v, 1, 64));
                    v = fmaxf(v, __shfl_xor(v, 2, 64));
                    v = fmaxf(v, __shfl_xor(v, 4, 64));
                    v = fmaxf(v, __shfl_xor(v, 8, 64));
                    mx[r] = v;
                    grow = grow || (v > m_st[mt][r]);
                }
                if (__ballot(grow)) {
                    #pragma unroll
                    for (int r = 0; r < 4; r++) {
                        float mn = fmaxf(m_st[mt][r], mx[r]);
                        float al = exp2f(m_st[mt][r] - mn);
                        m_st[mt][r] = mn;
                        Ol[mt][r] *= al;
                        #pragma unroll
                        for (int ct2 = 0; ct2 < 4; ct2++) O[mt][ct2][r] *= al;
                    }
                }
                #pragma unroll
                for (int c8 = 0; c8 < 8; c8++)
                    #pragma unroll
                    for (int r = 0; r < 4; r++)
                        S[c8][r] = exp2f(S[c8][r] - m_st[mt][r]);

                // ---- PV in two halves, reusing the wave-private P strip ----
                const int prow = w * 32 + mt * 16;
                #pragma unroll
                for (int half = 0; half < 2; half++) {
                    #pragma unroll
                    for (int ct = 0; ct < 4; ct++)
                        #pragma unroll
                        for (int r = 0; r < 4; r++)
                            P_lds[(prow + quad * 4 + r) * 72 + ct * 16 + t] =
                                (_Float16)S[half * 4 + ct][r];
                    f16x8 p0 = *(const f16x8*)&P_lds[(prow + t) * 72 + quad * 8];
                    f16x8 p1 = *(const f16x8*)&P_lds[(prow + t) * 72 + 32 + quad * 8];
                    #pragma unroll
                    for (int ct2 = 0; ct2 < 4; ct2++) {
                        int rowoff2 = (ct2 * 16 + t) * 64;
                        f16x8 v0 = *(const f16x8*)&Vt_lds[half][rowoff2 + rs0];
                        f16x8 v1 = *(const f16x8*)&Vt_lds[half][rowoff2 + rs1];
                        O[mt][ct2] = __builtin_amdgcn_mfma_f32_16x16x32_f16(p0, v0, O[mt][ct2], 0, 0, 0);
                        O[mt][ct2] = __builtin_amdgcn_mfma_f32_16x16x32_f16(p1, v1, O[mt][ct2], 0, 0, 0);
                    }
                    Ol[mt] = __builtin_amdgcn_mfma_f32_16x16x32_f16(p0, ones, Ol[mt], 0, 0, 0);
                    Ol[mt] = __builtin_amdgcn_mfma_f32_16x16x32_f16(p1, ones, Ol[mt], 0, 0, 0);
                }
            }
        }

        // epilogue: normalize, write [B][T][H*64] fp32
        #pragma unroll
        for (int mt = 0; mt < 2; mt++) {
            float* ob = out + ((size_t)b * TSEQ + qb * 128 + w * 32 + mt * 16 + quad * 4) * DMODEL
                      + h * 64;
            #pragma unroll
            for (int r = 0; r < 4; r++) {
                float inv = 1.0f / Ol[mt][r];
                #pragma unroll
                for (int ct2 = 0; ct2 < 4; ct2++)
                    ob[(size_t)r * DMODEL + ct2 * 16 + t] = O[mt][ct2][r] * inv;
            }
        }
    }
}

// ---------------------------------------------------------------------------
extern "C" void kernel_launch(void* const* d_in, const int* in_sizes, int n_in,
                              void* d_out, int out_size, void* d_ws, size_t ws_size,
                              hipStream_t stream)
{
    const float* x  = (const float*)d_in[0];
    const float* Wq = (const float*)d_in[1];
    const float* bq = (const float*)d_in[2];
    const float* Wk = (const float*)d_in[3];
    const float* bk = (const float*)d_in[4];
    const float* Wv = (const float*)d_in[5];
    const float* bv = (const float*)d_in[6];

    const size_t TEN = (size_t)MROWS * DMODEL;   // 8M
    const size_t WEN = (size_t)DMODEL * DMODEL;  // 1M
    short* Xhi = (short*)d_ws;
    short* Xlo = Xhi + TEN;
    short* Whi = Xlo + TEN;
    short* Wlo = Whi + 3 * WEN;
    short* Qhi = Wlo + 3 * WEN;
    short* Qlo = Qhi + TEN;
    short* Khi = Qlo + TEN;
    short* Klo = Khi + TEN;
    _Float16* VgT = (_Float16*)(Klo + TEN);
    float* out = (float*)d_out;

    int nsplit = (X_F4 + 3 * W_F4) / 256;
    split_all<<<nsplit, 256, 0, stream>>>(x, Wq, Wk, Wv, Xhi, Xlo, Whi, Wlo);

    dim3 gg(DMODEL / 128, MROWS / 128, 3);
    qkv_gemm_mfma<<<gg, 256, 0, stream>>>(Xhi, Xlo, Whi, Wlo, bq, bk, bv,
                                          Qhi, Qlo, Khi, Klo, VgT);

    dim3 ga(8, NBATCH * NHEAD);
    attn_fwd<<<ga, 256, 0, stream>>>(Qhi, Qlo, Khi, Klo, VgT, out);
}